// Round 14
// baseline (1354.093 us; speedup 1.0000x reference)
//
#include <hip/hip_runtime.h>
#include <cstdint>
#include <cstddef>

#define NPTS 8192
#define MCTR 2048
#define BATCH 4
#define KNB 32

typedef float v2f __attribute__((ext_vector_type(2)));

// wave-local LDS sync: all LDS ops of THIS WAVE complete; memory clobber stops
// compiler reordering. lgkmcnt is a per-wave counter, so this needs no barrier
// even with 4 waves per workgroup (their LDS regions are disjoint).
#define WSYNC() asm volatile("s_waitcnt lgkmcnt(0)" ::: "memory")

// ---- u32 wave max via DPP (identity 0, values >= 0), foldable to v_max_u32_dpp.
// row_shr:N pushes data to HIGHER lanes; max accumulates in lane 63. ----
__device__ __forceinline__ unsigned wave_max_u32(unsigned x) {
  unsigned t;
  t = (unsigned)__builtin_amdgcn_update_dpp(0, (int)x, 0x111, 0xf, 0xf, false);
  x = x > t ? x : t;
  t = (unsigned)__builtin_amdgcn_update_dpp(0, (int)x, 0x112, 0xf, 0xf, false);
  x = x > t ? x : t;
  t = (unsigned)__builtin_amdgcn_update_dpp(0, (int)x, 0x114, 0xf, 0xf, false);
  x = x > t ? x : t;
  t = (unsigned)__builtin_amdgcn_update_dpp(0, (int)x, 0x118, 0xf, 0xf, false);
  x = x > t ? x : t;
  t = (unsigned)__builtin_amdgcn_update_dpp(0, (int)x, 0x142, 0xa, 0xf, false);
  x = x > t ? x : t;
  t = (unsigned)__builtin_amdgcn_update_dpp(0, (int)x, 0x143, 0xc, 0xf, false);
  x = x > t ? x : t;
  return (unsigned)__builtin_amdgcn_readlane((int)x, 63);
}

// ---------- fused kernel (1024 threads/block) — R6 structure (1150us) + R14
// s_setprio role-split: active waves (the 1-2 whose update+DPP+atomic chain
// sets barrier-release time, and whose post-barrier gkey/lC4 reads are the
// next iteration's critical path) run at prio 1; idle skeleton waves at 0.
// The winner's owner wave is provably active in the selecting iteration
// (its slot has dd == global max => lb < cmax), so the elevated set always
// contains the critical wave. Pure scheduler hint — zero semantic change.
// blocks 0..3     : FPS. blocks 4..259: feature transpose. 260..267: weight prep.
__global__ __launch_bounds__(1024) void fused_kernel(
    const float* __restrict__ feats, float* __restrict__ featT,
    const float* __restrict__ W1, const float* __restrict__ W2,
    const float* __restrict__ W3, float* __restrict__ Wt,
    const float* __restrict__ coords, int* __restrict__ cidx,
    float* __restrict__ centers) {
  __shared__ __align__(16) float4 lC4[NPTS];  // 128 KiB (w = orig idx bits)
  __shared__ unsigned long long gkey[3];
  __shared__ int h[512];
  __shared__ int cur[512];
  __shared__ int s_slot0;
  const int bid = blockIdx.x;
  const int tid = threadIdx.x;

  if (bid >= 260) {  // ---- weight transpose path ----
    const int t = (bid - 260) * 1024 + tid;
    if (t < 2240) { int c = t >> 6, o = t & 63;  Wt[t] = W1[o * 35 + c]; }
    if (t < 4096) { int c = t >> 6, o = t & 63;  Wt[2240 + t] = W2[o * 64 + c]; }
    if (t < 8192) { int c = t >> 7, o = t & 127; Wt[6336 + t] = W3[o * 64 + c]; }
    return;
  }
  if (bid >= 4) {  // ---- feature transpose path (4 tiles per block) ----
    const int q = bid - 4;             // 0..255
    const int quarter = tid >> 8, t = tid & 255;
    const int bn = q * 4 + quarter;    // 0..1023
    const int b = bn >> 8;
    const int n0 = (bn & 255) * 32;
    float* tile = ((float*)lC4) + quarter * (32 * 33);
    const int tx = t & 31, ty = t >> 5;
    const float* src = feats + (size_t)b * 32 * NPTS;
#pragma unroll
    for (int s = 0; s < 4; ++s) {
      int f = ty + 8 * s;
      tile[f * 33 + tx] = src[(size_t)f * NPTS + n0 + tx];
    }
    __syncthreads();
    float* dst = featT + ((size_t)b * NPTS + n0) * 32;
#pragma unroll
    for (int s = 0; s < 4; ++s) {
      int n = ty + 8 * s;
      dst[n * 32 + tx] = tile[tx * 33 + n];
    }
    return;
  }

  // ---- FPS path (blocks 0..3) ----
  const int b = bid;
  const float* C = coords + (size_t)b * 3 * NPTS;
  // --- histogram (512 x-buckets, 8 points/thread) ---
  if (tid < 512) h[tid] = 0;
  __syncthreads();
  int bk[8];
#pragma unroll
  for (int j = 0; j < 8; ++j) {
    const int i = tid + j * 1024;
    const float x = C[i];
    int k = (int)(x * 512.0f);
    k = k < 0 ? 0 : (k > 511 ? 511 : k);
    bk[j] = k;
    atomicAdd(&h[k], 1);
  }
  __syncthreads();
  // --- Hillis-Steele inclusive scan over h (tid<512 participate) ---
  const int cnt = (tid < 512) ? h[tid] : 0;
  for (int s = 1; s < 512; s <<= 1) {
    int v = (tid >= s && tid < 512) ? h[tid - s] : 0;
    __syncthreads();
    if (tid < 512) h[tid] += v;
    __syncthreads();
  }
  if (tid < 512) cur[tid] = h[tid] - cnt;  // exclusive start of bucket tid
  __syncthreads();
  // --- scatter into LDS (within-bucket order nondeterministic; harmless) ---
#pragma unroll
  for (int j = 0; j < 8; ++j) {
    const int i = tid + j * 1024;
    const int pos = atomicAdd(&cur[bk[j]], 1);
    float4 v;
    v.x = C[i];
    v.y = C[NPTS + i];
    v.z = C[2 * NPTS + i];
    v.w = __int_as_float(i);  // ORIGINAL index, bit-stashed
    lC4[pos] = v;
  }
  if (tid < 3) gkey[tid] = 0ull;
  __syncthreads();
  // --- blocked read of owned slots (8 per thread) ---
  const int base = tid * 8;
  int og[8];
  v2f px[4], py[4], pz[4], dd[4];
#pragma unroll
  for (int p = 0; p < 4; ++p) {
    float4 c0 = lC4[base + 2 * p];
    float4 c1 = lC4[base + 2 * p + 1];
    px[p].x = c0.x; px[p].y = c1.x;
    py[p].x = c0.y; py[p].y = c1.y;
    pz[p].x = c0.z; pz[p].y = c1.z;
    og[2 * p] = __float_as_int(c0.w);
    og[2 * p + 1] = __float_as_int(c1.w);
    dd[p].x = __builtin_inff(); dd[p].y = __builtin_inff();
  }
#pragma unroll
  for (int j = 0; j < 8; ++j)
    if (og[j] == 0) s_slot0 = base + j;  // exactly one thread writes
  // exact bbox of owned points
  v2f xl = px[0], xh = px[0], yl = py[0], yh = py[0], zl = pz[0], zh = pz[0];
#pragma unroll
  for (int p = 1; p < 4; ++p) {
    xl = __builtin_elementwise_min(xl, px[p]); xh = __builtin_elementwise_max(xh, px[p]);
    yl = __builtin_elementwise_min(yl, py[p]); yh = __builtin_elementwise_max(yh, py[p]);
    zl = __builtin_elementwise_min(zl, pz[p]); zh = __builtin_elementwise_max(zh, pz[p]);
  }
  const float xlo = fminf(xl.x, xl.y), xhi = fmaxf(xh.x, xh.y);
  const float ylo = fminf(yl.x, yl.y), yhi = fmaxf(yh.x, yh.y);
  const float zlo = fminf(zl.x, zl.y), zhi = fmaxf(zh.x, zh.y);
  __syncthreads();
  float cmax = __builtin_inff();
  int amin = (og[0] << 3) | 0;
#pragma unroll
  for (int j = 1; j < 8; ++j) amin = min(amin, (og[j] << 3) | j);
  const int slot0 = s_slot0;
  float4 cc = lC4[slot0];
  float cx = cc.x, cy = cc.y, cz = cc.z;
  unsigned long long kreg[2];
  if (tid == 0)  // m=0: initial point, orig 0 (dist bits unused by writeback)
    kreg[0] = ((unsigned long long)(unsigned)8191 << 13) | (unsigned)slot0;
  // cached-fire state (all initialized on it=0: every lane active then)
  unsigned mydist = 0, mytail = 0;
  unsigned long long mykey = 0ull;
  bool fire = false;
  int gb = 0, gz = 2;  // atomic buffer / zero target (3-phase rotation)
  for (int it = 0; it < MCTR; ++it) {
    float dxm = fmaxf(fmaxf(xlo - cx, cx - xhi), 0.0f);
    float dym = fmaxf(fmaxf(ylo - cy, cy - yhi), 0.0f);
    float dzm = fmaxf(fmaxf(zlo - cz, cz - zhi), 0.0f);
    float lb = dxm * dxm + dym * dym + dzm * dzm;
    bool active = !(lb * 0.999999f >= cmax);  // margin makes skip provably exact
    const unsigned long long mk = __ballot(active ? 1 : 0);
    if (mk != 0ull) {  // wave has work: elevate priority (critical-path wave)
      __builtin_amdgcn_s_setprio(1);
      if (active) {
        v2f vcx, vcy, vcz;
        vcx.x = cx; vcx.y = cx;
        vcy.x = cy; vcy.y = cy;
        vcz.x = cz; vcz.y = cz;
        {
#pragma clang fp contract(off)
          // EXACT reference order per half: (dx*dx + dy*dy) + dz*dz, rn each
          // step, no FMA (contract off). Packed == scalar bit-exact.
#pragma unroll
          for (int p = 0; p < 4; ++p) {
            v2f dx = px[p] - vcx;
            v2f dy = py[p] - vcy;
            v2f dz = pz[p] - vcz;
            v2f d = (dx * dx + dy * dy) + dz * dz;
            dd[p] = __builtin_elementwise_min(dd[p], d);
          }
        }
        v2f m01 = __builtin_elementwise_max(dd[0], dd[1]);
        v2f m23 = __builtin_elementwise_max(dd[2], dd[3]);
        v2f mm = __builtin_elementwise_max(m01, m23);
        cmax = fmaxf(mm.x, mm.y);
        // min ORIGINAL idx among achievers — depth-3 tree
        const int I = 0x7fffffff;
        int c0 = min(dd[0].x == cmax ? ((og[0] << 3) | 0) : I,
                     dd[0].y == cmax ? ((og[1] << 3) | 1) : I);
        int c1 = min(dd[1].x == cmax ? ((og[2] << 3) | 2) : I,
                     dd[1].y == cmax ? ((og[3] << 3) | 3) : I);
        int c2 = min(dd[2].x == cmax ? ((og[4] << 3) | 4) : I,
                     dd[2].y == cmax ? ((og[5] << 3) | 5) : I);
        int c3 = min(dd[3].x == cmax ? ((og[6] << 3) | 6) : I,
                     dd[3].y == cmax ? ((og[7] << 3) | 7) : I);
        amin = min(min(c0, c1), min(c2, c3));
        mydist = __float_as_uint(cmax);
        mytail = ((unsigned)(8191 - (amin >> 3)) << 13) |
                 (unsigned)(base + (amin & 7));
        mykey = ((unsigned long long)mydist << 32) | mytail;
      }
      const unsigned gwd = wave_max_u32(mydist);
      fire = (mydist == gwd);
    } else {
      __builtin_amdgcn_s_setprio(0);  // idle skeleton wave: yield arbitration
    }
    // achiever lanes (fresh or cached) fire the lexicographic u64 key.
    if (fire) atomicMax(&gkey[gb], mykey);
    __syncthreads();
    const unsigned long long gk = gkey[gb];   // broadcast b64 read
    if (tid == 0) gkey[gz] = 0ull;            // reset: read again 2 barriers out
    if (((it + 1) >> 1) == tid) kreg[(it + 1) & 1] = gk;  // winner for m=it+1
    const int slot = (int)((unsigned)gk & 0x1fffu);
    float4 c2 = lC4[slot];  // ONE ds_read_b128, wave-uniform broadcast
    cx = c2.x; cy = c2.y; cz = c2.z;
    gb = gb == 2 ? 0 : gb + 1;
    gz = gz == 2 ? 0 : gz + 1;
  }
  __builtin_amdgcn_s_setprio(0);
  // coalesced writeback: thread t owns centers m = 2t..2t+1
#pragma unroll
  for (int r = 0; r < 2; ++r) {
    unsigned long long k = kreg[r];
    int orig = 8191 - (int)((k >> 13) & 0x1fff);
    int sl = (int)(k & 0x1fff);
    int m = 2 * tid + r;
    float4 c = lC4[sl];
    cidx[b * MCTR + m] = orig;
    centers[(size_t)b * 3 * MCTR + m] = c.x;
    centers[(size_t)b * 3 * MCTR + MCTR + m] = c.y;
    centers[(size_t)b * 3 * MCTR + 2 * MCTR + m] = c.z;
  }
}

// ---------- MLP helpers (XOR-swizzled LDS) — R11 16x4 tiling (proven best) ----
__device__ __forceinline__ int SW(int ch, int col) {
  return 32 * ch + (col ^ ((((ch) >> 2) & 7) << 2));
}

__device__ __forceinline__ void layerT(const float* __restrict__ X,
                                       const float* __restrict__ W, int ldw, int cin,
                                       float4 bias, int og, int kg, float acc[4][8]) {
  const float bv[4] = {bias.x, bias.y, bias.z, bias.w};
#pragma unroll
  for (int oi = 0; oi < 4; ++oi)
#pragma unroll
    for (int ki = 0; ki < 8; ++ki) acc[oi][ki] = bv[oi];
#pragma unroll 4
  for (int c = 0; c < cin; ++c) {
    const float4 xa = *(const float4*)(X + SW(c, 8 * kg));
    const float4 xb = *(const float4*)(X + SW(c, 8 * kg + 4));
    float4 w = *(const float4*)(W + ldw * c + 4 * og);
    const float wv[4] = {w.x, w.y, w.z, w.w};
    const float xv[8] = {xa.x, xa.y, xa.z, xa.w, xb.x, xb.y, xb.z, xb.w};
#pragma unroll
    for (int oi = 0; oi < 4; ++oi)
#pragma unroll
      for (int ki = 0; ki < 8; ++ki)
        acc[oi][ki] = fmaf(wv[oi], xv[ki], acc[oi][ki]);
  }
}

__device__ __forceinline__ void storeT(float* __restrict__ dst, int og, int kg,
                                       const float acc[4][8]) {
#pragma unroll
  for (int oi = 0; oi < 4; ++oi) {
    float4 va, vb;
    va.x = fmaxf(acc[oi][0], 0.f); va.y = fmaxf(acc[oi][1], 0.f);
    va.z = fmaxf(acc[oi][2], 0.f); va.w = fmaxf(acc[oi][3], 0.f);
    vb.x = fmaxf(acc[oi][4], 0.f); vb.y = fmaxf(acc[oi][5], 0.f);
    vb.z = fmaxf(acc[oi][6], 0.f); vb.w = fmaxf(acc[oi][7], 0.f);
    const int r = 4 * og + oi;
    *(float4*)(dst + SW(r, 8 * kg)) = va;
    *(float4*)(dst + SW(r, 8 * kg + 4)) = vb;
  }
}

// ---------- fused tail: ball query + MLP + direct transposed store ----------
// BYTE-EXACT R13 (best measured): 4 centers per 256-thread workgroup, one wave
// per center, R11 16x4 MLP tiling, 4-pts/lane float4 ball query.
__global__ __launch_bounds__(256) void tail_kernel(
    const float* __restrict__ coords, const float* __restrict__ featT,
    const float* __restrict__ Wt, const float* __restrict__ b1,
    const float* __restrict__ b2, const float* __restrict__ b3,
    const int* __restrict__ cidx, float* __restrict__ out) {
  const int w = threadIdx.x >> 6;
  const int lane = threadIdx.x & 63;
  const int g = blockIdx.x * 4 + w;
  const int b = g >> 11;
  const int m = g & 2047;
  __shared__ __align__(16) float Sall[4][2048];  // 8KB per wave, swizzled
  __shared__ int nball[4][32];
  float* S = Sall[w];
  int* nbuf = nball[w];
  const float* C = coords + (size_t)b * 3 * NPTS;
  const int ci = cidx[g];
  // ---- ball query: 4 pts/lane/round, float4 coalesced, exact index order ----
  const float cx = C[ci], cy = C[NPTS + ci], cz = C[2 * NPTS + ci];
  // python double 0.2*0.2 demoted to f32 == 0x3D23D70A (NOT 0.2f*0.2f!)
  const float R2 = (float)(0.2 * 0.2);
  const float4* X4 = (const float4*)(C);
  const float4* Y4 = (const float4*)(C + NPTS);
  const float4* Z4 = (const float4*)(C + 2 * NPTS);
  int count = 0;
  float4 xx = X4[lane], yy = Y4[lane], zz = Z4[lane];
  for (int base2 = 0; base2 < NPTS && count < 32; base2 += 256) {
    float4 nx4, ny4, nz4;
    nx4.x = nx4.y = nx4.z = nx4.w = 0.f;
    ny4 = nx4; nz4 = nx4;
    if (base2 + 256 < NPTS) {  // prefetch next round while this round resolves
      const int li = ((base2 + 256) >> 2) + lane;
      nx4 = X4[li]; ny4 = Y4[li]; nz4 = Z4[li];
    }
    // per-point in-radius tests, EXACT original op sequence per point
    bool q[4];
    {
      const float px4[4] = {xx.x, xx.y, xx.z, xx.w};
      const float py4[4] = {yy.x, yy.y, yy.z, yy.w};
      const float pz4[4] = {zz.x, zz.y, zz.z, zz.w};
#pragma unroll
      for (int j = 0; j < 4; ++j) {
        float dx = __fsub_rn(cx, px4[j]);
        float dy = __fsub_rn(cy, py4[j]);
        float dz = __fsub_rn(cz, pz4[j]);
        float d2 = __fadd_rn(__fadd_rn(__fmul_rn(dx, dx), __fmul_rn(dy, dy)),
                             __fmul_rn(dz, dz));
        q[j] = d2 < R2;
      }
    }
    const unsigned long long m0 = __ballot(q[0] ? 1 : 0);
    const unsigned long long m1 = __ballot(q[1] ? 1 : 0);
    const unsigned long long m2 = __ballot(q[2] ? 1 : 0);
    const unsigned long long m3 = __ballot(q[3] ? 1 : 0);
    // position of point (lane, j): idx = base2 + 4*lane + j — lane-major order
    const unsigned long long below = (1ull << lane) - 1ull;
    int p0 = count + (int)__popcll(m0 & below) + (int)__popcll(m1 & below) +
             (int)__popcll(m2 & below) + (int)__popcll(m3 & below);
    int p1 = p0 + (q[0] ? 1 : 0);
    int p2 = p1 + (q[1] ? 1 : 0);
    int p3 = p2 + (q[2] ? 1 : 0);
    const int bi = base2 + 4 * lane;
    if (q[0] && p0 < 32) nbuf[p0] = bi;
    if (q[1] && p1 < 32) nbuf[p1] = bi + 1;
    if (q[2] && p2 < 32) nbuf[p2] = bi + 2;
    if (q[3] && p3 < 32) nbuf[p3] = bi + 3;
    count += (int)__popcll(m0) + (int)__popcll(m1) + (int)__popcll(m2) +
             (int)__popcll(m3);
    xx = nx4; yy = ny4; zz = nz4;
  }
  WSYNC();
  const int cnt = count < 32 ? count : 32;
  const int first = (count > 0) ? nbuf[0] : 0;
  // ---- MLP input staging into S (verbatim R11) ----
  const int og = lane & 15, kg = lane >> 4;
  if (lane < 32) {
    const int n = (lane < cnt) ? nbuf[lane] : first;
    S[SW(0, lane)] = C[n] - cx;
    S[SW(1, lane)] = C[NPTS + n] - cy;
    S[SW(2, lane)] = C[2 * NPTS + n] - cz;
    const float4* f = (const float4*)(featT + ((size_t)b * NPTS + n) * 32);
#pragma unroll
    for (int q2 = 0; q2 < 4; ++q2) {
      float4 v = f[q2];
      S[SW(3 + 4 * q2, lane)] = v.x;
      S[SW(4 + 4 * q2, lane)] = v.y;
      S[SW(5 + 4 * q2, lane)] = v.z;
      S[SW(6 + 4 * q2, lane)] = v.w;
    }
  } else {
    const int k = lane - 32;
    const int n = (k < cnt) ? nbuf[k] : first;
    const float4* f = (const float4*)(featT + ((size_t)b * NPTS + n) * 32);
#pragma unroll
    for (int q2 = 4; q2 < 8; ++q2) {
      float4 v = f[q2];
      S[SW(3 + 4 * q2, k)] = v.x;
      S[SW(4 + 4 * q2, k)] = v.y;
      S[SW(5 + 4 * q2, k)] = v.z;
      S[SW(6 + 4 * q2, k)] = v.w;
    }
  }
  WSYNC();
  float acc[4][8];
  // layer1: read S (35 ch) -> acc; reads all consumed before in-place store
  layerT(S, Wt, 64, 35, *(const float4*)(b1 + 4 * og), og, kg, acc);
  WSYNC();  // reads drained before overwrite
  storeT(S, og, kg, acc);
  WSYNC();  // writes visible before next layer reads
  // layer2: read S (64 ch) -> acc -> in-place store
  layerT(S, Wt + 2240, 64, 64, *(const float4*)(b2 + 4 * og), og, kg, acc);
  WSYNC();
  storeT(S, og, kg, acc);
  WSYNC();
  // ---- layer 3 (reads S twice, no LDS writes) + max-over-k + direct
  // transposed store to out (B,128,M) ----
  float* op = out + (size_t)b * 128 * MCTR + m;
#pragma unroll 1
  for (int hh = 0; hh < 2; ++hh) {
    layerT(S, Wt + 6336 + 64 * hh, 128, 64,
           *(const float4*)(b3 + 64 * hh + 4 * og), og, kg, acc);
    float rp[4];
#pragma unroll
    for (int oi = 0; oi < 4; ++oi) {
      float mm = 0.f;
#pragma unroll
      for (int ki = 0; ki < 8; ++ki) mm = fmaxf(mm, acc[oi][ki]);
      mm = fmaxf(mm, __shfl_xor(mm, 16));
      mm = fmaxf(mm, __shfl_xor(mm, 32));
      rp[oi] = mm;
    }
    if (kg == 0) {
#pragma unroll
      for (int oi = 0; oi < 4; ++oi)
        op[(size_t)(64 * hh + 4 * og + oi) * MCTR] = rp[oi];
    }
  }
}

extern "C" void kernel_launch(void* const* d_in, const int* in_sizes, int n_in,
                              void* d_out, int out_size, void* d_ws, size_t ws_size,
                              hipStream_t stream) {
  (void)in_sizes; (void)n_in; (void)out_size; (void)ws_size;
  const float* feats = (const float*)d_in[0];
  const float* coords = (const float*)d_in[1];
  const float* W1 = (const float*)d_in[2];
  const float* b1 = (const float*)d_in[3];
  const float* W2 = (const float*)d_in[4];
  const float* b2 = (const float*)d_in[5];
  const float* W3 = (const float*)d_in[6];
  const float* b3 = (const float*)d_in[7];
  float* out = (float*)d_out;
  float* centers = out + (size_t)BATCH * 128 * MCTR;

  float* ws_f = (float*)d_ws;
  float* featT = ws_f;                         // 1,048,576 f
  float* Wt = ws_f + 1048576;                  //    14,528 f
  int* cidx = (int*)(ws_f + 1048576 + 14528);  //     8,192 i

  // blocks: 0..3 fps | 4..259 featT | 260..267 prep — transposes overlap fps
  fused_kernel<<<268, 1024, 0, stream>>>(feats, featT, W1, W2, W3, Wt, coords, cidx,
                                         centers);
  // fused tail: 4 centers / 256-thread workgroup, one wave per center,
  // R11 MLP tiling + 4-pts/lane float4 ball query
  tail_kernel<<<BATCH * MCTR / 4, 256, 0, stream>>>(coords, featT, Wt, b1, b2, b3,
                                                    cidx, out);
}

// Round 15
// 1306.547 us; speedup vs baseline: 1.0364x; 1.0364x over previous
//
#include <hip/hip_runtime.h>
#include <cstdint>
#include <cstddef>

#define NPTS 8192
#define MCTR 2048
#define BATCH 4
#define KNB 32

typedef float v2f __attribute__((ext_vector_type(2)));

// wave-local LDS sync: all LDS ops of THIS WAVE complete; memory clobber stops
// compiler reordering. lgkmcnt is a per-wave counter, so this needs no barrier
// even with 4 waves per workgroup (their LDS regions are disjoint).
#define WSYNC() asm volatile("s_waitcnt lgkmcnt(0)" ::: "memory")

// ---- u32 wave max via DPP (identity 0, values >= 0), foldable to v_max_u32_dpp.
// row_shr:N pushes data to HIGHER lanes; max accumulates in lane 63. ----
__device__ __forceinline__ unsigned wave_max_u32(unsigned x) {
  unsigned t;
  t = (unsigned)__builtin_amdgcn_update_dpp(0, (int)x, 0x111, 0xf, 0xf, false);
  x = x > t ? x : t;
  t = (unsigned)__builtin_amdgcn_update_dpp(0, (int)x, 0x112, 0xf, 0xf, false);
  x = x > t ? x : t;
  t = (unsigned)__builtin_amdgcn_update_dpp(0, (int)x, 0x114, 0xf, 0xf, false);
  x = x > t ? x : t;
  t = (unsigned)__builtin_amdgcn_update_dpp(0, (int)x, 0x118, 0xf, 0xf, false);
  x = x > t ? x : t;
  t = (unsigned)__builtin_amdgcn_update_dpp(0, (int)x, 0x142, 0xa, 0xf, false);
  x = x > t ? x : t;
  t = (unsigned)__builtin_amdgcn_update_dpp(0, (int)x, 0x143, 0xc, 0xf, false);
  x = x > t ? x : t;
  return (unsigned)__builtin_amdgcn_readlane((int)x, 63);
}

// ---------- fused kernel (1024 threads/block) — BYTE-EXACT R6 (measured 1150us).
// Producer/consumer overlap (R7/R8) was breakeven: 252 CUs of polling+FMA work
// throttles boost ~13%, cancelling the absorbed tail. setprio role-split (R14)
// regressed +55us (arbitration theory refuted). Serial at full boost, no
// scheduler hints = the measured floor for this 2048-step dependence chain.
// blocks 0..3     : FPS. blocks 4..259: feature transpose. 260..267: weight prep.
__global__ __launch_bounds__(1024) void fused_kernel(
    const float* __restrict__ feats, float* __restrict__ featT,
    const float* __restrict__ W1, const float* __restrict__ W2,
    const float* __restrict__ W3, float* __restrict__ Wt,
    const float* __restrict__ coords, int* __restrict__ cidx,
    float* __restrict__ centers) {
  __shared__ __align__(16) float4 lC4[NPTS];  // 128 KiB (w = orig idx bits)
  __shared__ unsigned long long gkey[3];
  __shared__ int h[512];
  __shared__ int cur[512];
  __shared__ int s_slot0;
  const int bid = blockIdx.x;
  const int tid = threadIdx.x;

  if (bid >= 260) {  // ---- weight transpose path ----
    const int t = (bid - 260) * 1024 + tid;
    if (t < 2240) { int c = t >> 6, o = t & 63;  Wt[t] = W1[o * 35 + c]; }
    if (t < 4096) { int c = t >> 6, o = t & 63;  Wt[2240 + t] = W2[o * 64 + c]; }
    if (t < 8192) { int c = t >> 7, o = t & 127; Wt[6336 + t] = W3[o * 64 + c]; }
    return;
  }
  if (bid >= 4) {  // ---- feature transpose path (4 tiles per block) ----
    const int q = bid - 4;             // 0..255
    const int quarter = tid >> 8, t = tid & 255;
    const int bn = q * 4 + quarter;    // 0..1023
    const int b = bn >> 8;
    const int n0 = (bn & 255) * 32;
    float* tile = ((float*)lC4) + quarter * (32 * 33);
    const int tx = t & 31, ty = t >> 5;
    const float* src = feats + (size_t)b * 32 * NPTS;
#pragma unroll
    for (int s = 0; s < 4; ++s) {
      int f = ty + 8 * s;
      tile[f * 33 + tx] = src[(size_t)f * NPTS + n0 + tx];
    }
    __syncthreads();
    float* dst = featT + ((size_t)b * NPTS + n0) * 32;
#pragma unroll
    for (int s = 0; s < 4; ++s) {
      int n = ty + 8 * s;
      dst[n * 32 + tx] = tile[tx * 33 + n];
    }
    return;
  }

  // ---- FPS path (blocks 0..3) ----
  const int b = bid;
  const float* C = coords + (size_t)b * 3 * NPTS;
  // --- histogram (512 x-buckets, 8 points/thread) ---
  if (tid < 512) h[tid] = 0;
  __syncthreads();
  int bk[8];
#pragma unroll
  for (int j = 0; j < 8; ++j) {
    const int i = tid + j * 1024;
    const float x = C[i];
    int k = (int)(x * 512.0f);
    k = k < 0 ? 0 : (k > 511 ? 511 : k);
    bk[j] = k;
    atomicAdd(&h[k], 1);
  }
  __syncthreads();
  // --- Hillis-Steele inclusive scan over h (tid<512 participate) ---
  const int cnt = (tid < 512) ? h[tid] : 0;
  for (int s = 1; s < 512; s <<= 1) {
    int v = (tid >= s && tid < 512) ? h[tid - s] : 0;
    __syncthreads();
    if (tid < 512) h[tid] += v;
    __syncthreads();
  }
  if (tid < 512) cur[tid] = h[tid] - cnt;  // exclusive start of bucket tid
  __syncthreads();
  // --- scatter into LDS (within-bucket order nondeterministic; harmless) ---
#pragma unroll
  for (int j = 0; j < 8; ++j) {
    const int i = tid + j * 1024;
    const int pos = atomicAdd(&cur[bk[j]], 1);
    float4 v;
    v.x = C[i];
    v.y = C[NPTS + i];
    v.z = C[2 * NPTS + i];
    v.w = __int_as_float(i);  // ORIGINAL index, bit-stashed
    lC4[pos] = v;
  }
  if (tid < 3) gkey[tid] = 0ull;
  __syncthreads();
  // --- blocked read of owned slots (8 per thread) ---
  const int base = tid * 8;
  int og[8];
  v2f px[4], py[4], pz[4], dd[4];
#pragma unroll
  for (int p = 0; p < 4; ++p) {
    float4 c0 = lC4[base + 2 * p];
    float4 c1 = lC4[base + 2 * p + 1];
    px[p].x = c0.x; px[p].y = c1.x;
    py[p].x = c0.y; py[p].y = c1.y;
    pz[p].x = c0.z; pz[p].y = c1.z;
    og[2 * p] = __float_as_int(c0.w);
    og[2 * p + 1] = __float_as_int(c1.w);
    dd[p].x = __builtin_inff(); dd[p].y = __builtin_inff();
  }
#pragma unroll
  for (int j = 0; j < 8; ++j)
    if (og[j] == 0) s_slot0 = base + j;  // exactly one thread writes
  // exact bbox of owned points
  v2f xl = px[0], xh = px[0], yl = py[0], yh = py[0], zl = pz[0], zh = pz[0];
#pragma unroll
  for (int p = 1; p < 4; ++p) {
    xl = __builtin_elementwise_min(xl, px[p]); xh = __builtin_elementwise_max(xh, px[p]);
    yl = __builtin_elementwise_min(yl, py[p]); yh = __builtin_elementwise_max(yh, py[p]);
    zl = __builtin_elementwise_min(zl, pz[p]); zh = __builtin_elementwise_max(zh, pz[p]);
  }
  const float xlo = fminf(xl.x, xl.y), xhi = fmaxf(xh.x, xh.y);
  const float ylo = fminf(yl.x, yl.y), yhi = fmaxf(yh.x, yh.y);
  const float zlo = fminf(zl.x, zl.y), zhi = fmaxf(zh.x, zh.y);
  __syncthreads();
  float cmax = __builtin_inff();
  int amin = (og[0] << 3) | 0;
#pragma unroll
  for (int j = 1; j < 8; ++j) amin = min(amin, (og[j] << 3) | j);
  const int slot0 = s_slot0;
  float4 cc = lC4[slot0];
  float cx = cc.x, cy = cc.y, cz = cc.z;
  unsigned long long kreg[2];
  if (tid == 0)  // m=0: initial point, orig 0 (dist bits unused by writeback)
    kreg[0] = ((unsigned long long)(unsigned)8191 << 13) | (unsigned)slot0;
  // cached-fire state (all initialized on it=0: every lane active then)
  unsigned mydist = 0, mytail = 0;
  unsigned long long mykey = 0ull;
  bool fire = false;
  int gb = 0, gz = 2;  // atomic buffer / zero target (3-phase rotation)
  for (int it = 0; it < MCTR; ++it) {
    float dxm = fmaxf(fmaxf(xlo - cx, cx - xhi), 0.0f);
    float dym = fmaxf(fmaxf(ylo - cy, cy - yhi), 0.0f);
    float dzm = fmaxf(fmaxf(zlo - cz, cz - zhi), 0.0f);
    float lb = dxm * dxm + dym * dym + dzm * dzm;
    bool active = !(lb * 0.999999f >= cmax);  // margin makes skip provably exact
    const unsigned long long mk = __ballot(active ? 1 : 0);
    if (mk != 0ull) {  // wave has work: refresh update + DPP reduce + fire set
      if (active) {
        v2f vcx, vcy, vcz;
        vcx.x = cx; vcx.y = cx;
        vcy.x = cy; vcy.y = cy;
        vcz.x = cz; vcz.y = cz;
        {
#pragma clang fp contract(off)
          // EXACT reference order per half: (dx*dx + dy*dy) + dz*dz, rn each
          // step, no FMA (contract off). Packed == scalar bit-exact.
#pragma unroll
          for (int p = 0; p < 4; ++p) {
            v2f dx = px[p] - vcx;
            v2f dy = py[p] - vcy;
            v2f dz = pz[p] - vcz;
            v2f d = (dx * dx + dy * dy) + dz * dz;
            dd[p] = __builtin_elementwise_min(dd[p], d);
          }
        }
        v2f m01 = __builtin_elementwise_max(dd[0], dd[1]);
        v2f m23 = __builtin_elementwise_max(dd[2], dd[3]);
        v2f mm = __builtin_elementwise_max(m01, m23);
        cmax = fmaxf(mm.x, mm.y);
        // min ORIGINAL idx among achievers — depth-3 tree
        const int I = 0x7fffffff;
        int c0 = min(dd[0].x == cmax ? ((og[0] << 3) | 0) : I,
                     dd[0].y == cmax ? ((og[1] << 3) | 1) : I);
        int c1 = min(dd[1].x == cmax ? ((og[2] << 3) | 2) : I,
                     dd[1].y == cmax ? ((og[3] << 3) | 3) : I);
        int c2 = min(dd[2].x == cmax ? ((og[4] << 3) | 4) : I,
                     dd[2].y == cmax ? ((og[5] << 3) | 5) : I);
        int c3 = min(dd[3].x == cmax ? ((og[6] << 3) | 6) : I,
                     dd[3].y == cmax ? ((og[7] << 3) | 7) : I);
        amin = min(min(c0, c1), min(c2, c3));
        mydist = __float_as_uint(cmax);
        mytail = ((unsigned)(8191 - (amin >> 3)) << 13) |
                 (unsigned)(base + (amin & 7));
        mykey = ((unsigned long long)mydist << 32) | mytail;
      }
      const unsigned gwd = wave_max_u32(mydist);
      fire = (mydist == gwd);
    }
    // achiever lanes (fresh or cached) fire the lexicographic u64 key.
    if (fire) atomicMax(&gkey[gb], mykey);
    __syncthreads();
    const unsigned long long gk = gkey[gb];   // broadcast b64 read
    if (tid == 0) gkey[gz] = 0ull;            // reset: read again 2 barriers out
    if (((it + 1) >> 1) == tid) kreg[(it + 1) & 1] = gk;  // winner for m=it+1
    const int slot = (int)((unsigned)gk & 0x1fffu);
    float4 c2 = lC4[slot];  // ONE ds_read_b128, wave-uniform broadcast
    cx = c2.x; cy = c2.y; cz = c2.z;
    gb = gb == 2 ? 0 : gb + 1;
    gz = gz == 2 ? 0 : gz + 1;
  }
  // coalesced writeback: thread t owns centers m = 2t..2t+1
#pragma unroll
  for (int r = 0; r < 2; ++r) {
    unsigned long long k = kreg[r];
    int orig = 8191 - (int)((k >> 13) & 0x1fff);
    int sl = (int)(k & 0x1fff);
    int m = 2 * tid + r;
    float4 c = lC4[sl];
    cidx[b * MCTR + m] = orig;
    centers[(size_t)b * 3 * MCTR + m] = c.x;
    centers[(size_t)b * 3 * MCTR + MCTR + m] = c.y;
    centers[(size_t)b * 3 * MCTR + 2 * MCTR + m] = c.z;
  }
}

// ---------- MLP helpers (XOR-swizzled LDS) — R11 16x4 tiling (proven best) ----
__device__ __forceinline__ int SW(int ch, int col) {
  return 32 * ch + (col ^ ((((ch) >> 2) & 7) << 2));
}

__device__ __forceinline__ void layerT(const float* __restrict__ X,
                                       const float* __restrict__ W, int ldw, int cin,
                                       float4 bias, int og, int kg, float acc[4][8]) {
  const float bv[4] = {bias.x, bias.y, bias.z, bias.w};
#pragma unroll
  for (int oi = 0; oi < 4; ++oi)
#pragma unroll
    for (int ki = 0; ki < 8; ++ki) acc[oi][ki] = bv[oi];
#pragma unroll 4
  for (int c = 0; c < cin; ++c) {
    const float4 xa = *(const float4*)(X + SW(c, 8 * kg));
    const float4 xb = *(const float4*)(X + SW(c, 8 * kg + 4));
    float4 w = *(const float4*)(W + ldw * c + 4 * og);
    const float wv[4] = {w.x, w.y, w.z, w.w};
    const float xv[8] = {xa.x, xa.y, xa.z, xa.w, xb.x, xb.y, xb.z, xb.w};
#pragma unroll
    for (int oi = 0; oi < 4; ++oi)
#pragma unroll
      for (int ki = 0; ki < 8; ++ki)
        acc[oi][ki] = fmaf(wv[oi], xv[ki], acc[oi][ki]);
  }
}

__device__ __forceinline__ void storeT(float* __restrict__ dst, int og, int kg,
                                       const float acc[4][8]) {
#pragma unroll
  for (int oi = 0; oi < 4; ++oi) {
    float4 va, vb;
    va.x = fmaxf(acc[oi][0], 0.f); va.y = fmaxf(acc[oi][1], 0.f);
    va.z = fmaxf(acc[oi][2], 0.f); va.w = fmaxf(acc[oi][3], 0.f);
    vb.x = fmaxf(acc[oi][4], 0.f); vb.y = fmaxf(acc[oi][5], 0.f);
    vb.z = fmaxf(acc[oi][6], 0.f); vb.w = fmaxf(acc[oi][7], 0.f);
    const int r = 4 * og + oi;
    *(float4*)(dst + SW(r, 8 * kg)) = va;
    *(float4*)(dst + SW(r, 8 * kg + 4)) = vb;
  }
}

// ---------- fused tail: ball query + MLP + direct transposed store ----------
// BYTE-EXACT R13 (best measured): 4 centers per 256-thread workgroup, one wave
// per center, R11 16x4 MLP tiling, 4-pts/lane float4 ball query.
__global__ __launch_bounds__(256) void tail_kernel(
    const float* __restrict__ coords, const float* __restrict__ featT,
    const float* __restrict__ Wt, const float* __restrict__ b1,
    const float* __restrict__ b2, const float* __restrict__ b3,
    const int* __restrict__ cidx, float* __restrict__ out) {
  const int w = threadIdx.x >> 6;
  const int lane = threadIdx.x & 63;
  const int g = blockIdx.x * 4 + w;
  const int b = g >> 11;
  const int m = g & 2047;
  __shared__ __align__(16) float Sall[4][2048];  // 8KB per wave, swizzled
  __shared__ int nball[4][32];
  float* S = Sall[w];
  int* nbuf = nball[w];
  const float* C = coords + (size_t)b * 3 * NPTS;
  const int ci = cidx[g];
  // ---- ball query: 4 pts/lane/round, float4 coalesced, exact index order ----
  const float cx = C[ci], cy = C[NPTS + ci], cz = C[2 * NPTS + ci];
  // python double 0.2*0.2 demoted to f32 == 0x3D23D70A (NOT 0.2f*0.2f!)
  const float R2 = (float)(0.2 * 0.2);
  const float4* X4 = (const float4*)(C);
  const float4* Y4 = (const float4*)(C + NPTS);
  const float4* Z4 = (const float4*)(C + 2 * NPTS);
  int count = 0;
  float4 xx = X4[lane], yy = Y4[lane], zz = Z4[lane];
  for (int base2 = 0; base2 < NPTS && count < 32; base2 += 256) {
    float4 nx4, ny4, nz4;
    nx4.x = nx4.y = nx4.z = nx4.w = 0.f;
    ny4 = nx4; nz4 = nx4;
    if (base2 + 256 < NPTS) {  // prefetch next round while this round resolves
      const int li = ((base2 + 256) >> 2) + lane;
      nx4 = X4[li]; ny4 = Y4[li]; nz4 = Z4[li];
    }
    // per-point in-radius tests, EXACT original op sequence per point
    bool q[4];
    {
      const float px4[4] = {xx.x, xx.y, xx.z, xx.w};
      const float py4[4] = {yy.x, yy.y, yy.z, yy.w};
      const float pz4[4] = {zz.x, zz.y, zz.z, zz.w};
#pragma unroll
      for (int j = 0; j < 4; ++j) {
        float dx = __fsub_rn(cx, px4[j]);
        float dy = __fsub_rn(cy, py4[j]);
        float dz = __fsub_rn(cz, pz4[j]);
        float d2 = __fadd_rn(__fadd_rn(__fmul_rn(dx, dx), __fmul_rn(dy, dy)),
                             __fmul_rn(dz, dz));
        q[j] = d2 < R2;
      }
    }
    const unsigned long long m0 = __ballot(q[0] ? 1 : 0);
    const unsigned long long m1 = __ballot(q[1] ? 1 : 0);
    const unsigned long long m2 = __ballot(q[2] ? 1 : 0);
    const unsigned long long m3 = __ballot(q[3] ? 1 : 0);
    // position of point (lane, j): idx = base2 + 4*lane + j — lane-major order
    const unsigned long long below = (1ull << lane) - 1ull;
    int p0 = count + (int)__popcll(m0 & below) + (int)__popcll(m1 & below) +
             (int)__popcll(m2 & below) + (int)__popcll(m3 & below);
    int p1 = p0 + (q[0] ? 1 : 0);
    int p2 = p1 + (q[1] ? 1 : 0);
    int p3 = p2 + (q[2] ? 1 : 0);
    const int bi = base2 + 4 * lane;
    if (q[0] && p0 < 32) nbuf[p0] = bi;
    if (q[1] && p1 < 32) nbuf[p1] = bi + 1;
    if (q[2] && p2 < 32) nbuf[p2] = bi + 2;
    if (q[3] && p3 < 32) nbuf[p3] = bi + 3;
    count += (int)__popcll(m0) + (int)__popcll(m1) + (int)__popcll(m2) +
             (int)__popcll(m3);
    xx = nx4; yy = ny4; zz = nz4;
  }
  WSYNC();
  const int cnt = count < 32 ? count : 32;
  const int first = (count > 0) ? nbuf[0] : 0;
  // ---- MLP input staging into S (verbatim R11) ----
  const int og = lane & 15, kg = lane >> 4;
  if (lane < 32) {
    const int n = (lane < cnt) ? nbuf[lane] : first;
    S[SW(0, lane)] = C[n] - cx;
    S[SW(1, lane)] = C[NPTS + n] - cy;
    S[SW(2, lane)] = C[2 * NPTS + n] - cz;
    const float4* f = (const float4*)(featT + ((size_t)b * NPTS + n) * 32);
#pragma unroll
    for (int q2 = 0; q2 < 4; ++q2) {
      float4 v = f[q2];
      S[SW(3 + 4 * q2, lane)] = v.x;
      S[SW(4 + 4 * q2, lane)] = v.y;
      S[SW(5 + 4 * q2, lane)] = v.z;
      S[SW(6 + 4 * q2, lane)] = v.w;
    }
  } else {
    const int k = lane - 32;
    const int n = (k < cnt) ? nbuf[k] : first;
    const float4* f = (const float4*)(featT + ((size_t)b * NPTS + n) * 32);
#pragma unroll
    for (int q2 = 4; q2 < 8; ++q2) {
      float4 v = f[q2];
      S[SW(3 + 4 * q2, k)] = v.x;
      S[SW(4 + 4 * q2, k)] = v.y;
      S[SW(5 + 4 * q2, k)] = v.z;
      S[SW(6 + 4 * q2, k)] = v.w;
    }
  }
  WSYNC();
  float acc[4][8];
  // layer1: read S (35 ch) -> acc; reads all consumed before in-place store
  layerT(S, Wt, 64, 35, *(const float4*)(b1 + 4 * og), og, kg, acc);
  WSYNC();  // reads drained before overwrite
  storeT(S, og, kg, acc);
  WSYNC();  // writes visible before next layer reads
  // layer2: read S (64 ch) -> acc -> in-place store
  layerT(S, Wt + 2240, 64, 64, *(const float4*)(b2 + 4 * og), og, kg, acc);
  WSYNC();
  storeT(S, og, kg, acc);
  WSYNC();
  // ---- layer 3 (reads S twice, no LDS writes) + max-over-k + direct
  // transposed store to out (B,128,M) ----
  float* op = out + (size_t)b * 128 * MCTR + m;
#pragma unroll 1
  for (int hh = 0; hh < 2; ++hh) {
    layerT(S, Wt + 6336 + 64 * hh, 128, 64,
           *(const float4*)(b3 + 64 * hh + 4 * og), og, kg, acc);
    float rp[4];
#pragma unroll
    for (int oi = 0; oi < 4; ++oi) {
      float mm = 0.f;
#pragma unroll
      for (int ki = 0; ki < 8; ++ki) mm = fmaxf(mm, acc[oi][ki]);
      mm = fmaxf(mm, __shfl_xor(mm, 16));
      mm = fmaxf(mm, __shfl_xor(mm, 32));
      rp[oi] = mm;
    }
    if (kg == 0) {
#pragma unroll
      for (int oi = 0; oi < 4; ++oi)
        op[(size_t)(64 * hh + 4 * og + oi) * MCTR] = rp[oi];
    }
  }
}

extern "C" void kernel_launch(void* const* d_in, const int* in_sizes, int n_in,
                              void* d_out, int out_size, void* d_ws, size_t ws_size,
                              hipStream_t stream) {
  (void)in_sizes; (void)n_in; (void)out_size; (void)ws_size;
  const float* feats = (const float*)d_in[0];
  const float* coords = (const float*)d_in[1];
  const float* W1 = (const float*)d_in[2];
  const float* b1 = (const float*)d_in[3];
  const float* W2 = (const float*)d_in[4];
  const float* b2 = (const float*)d_in[5];
  const float* W3 = (const float*)d_in[6];
  const float* b3 = (const float*)d_in[7];
  float* out = (float*)d_out;
  float* centers = out + (size_t)BATCH * 128 * MCTR;

  float* ws_f = (float*)d_ws;
  float* featT = ws_f;                         // 1,048,576 f
  float* Wt = ws_f + 1048576;                  //    14,528 f
  int* cidx = (int*)(ws_f + 1048576 + 14528);  //     8,192 i

  // blocks: 0..3 fps | 4..259 featT | 260..267 prep — transposes overlap fps
  fused_kernel<<<268, 1024, 0, stream>>>(feats, featT, W1, W2, W3, Wt, coords, cidx,
                                         centers);
  // fused tail: 4 centers / 256-thread workgroup, one wave per center,
  // R11 MLP tiling + 4-pts/lane float4 ball query
  tail_kernel<<<BATCH * MCTR / 4, 256, 0, stream>>>(coords, featT, Wt, b1, b2, b3,
                                                    cidx, out);
}